// Round 3
// baseline (574.391 us; speedup 1.0000x reference)
//
#include <hip/hip_runtime.h>

// TopK MoE classifier: B=8192, D=4096, E=16, O=512, top-2.
//  k0: we_transpose  W_e [E][D][O] f32 -> Wbt [E][O][D] bf16
//  k1: router fp32 (exact top-2 parity) + fused feat f32->bf16 cvt (featbf)
//      -- no LDS; deep-MLP float4 streaming; W_r straight from L1/L2
//  k2: moe_gemm grouped bf16 MFMA, 128x128 tile, BK=64, dbuf LDS,
//      global_load_lds staging w/ source-side XOR swizzle, 1 barrier/K-step
//  k3: finalize balance loss
// ws: [0,64Mi) Wbt | [64Mi,128Mi) featbf | tokL | wgtL | cnt | pisum

#define B_ 8192
#define D_ 4096
#define E_ 16
#define O_ 512
#define BK 64

typedef unsigned int uint32;
typedef unsigned short ushort_t;
typedef __bf16 bf16_t;
typedef bf16_t bf16x8 __attribute__((ext_vector_type(8)));
typedef float f32x4 __attribute__((ext_vector_type(4)));

__device__ __forceinline__ uint32 bf16_rne(float x) {
  uint32 u = __float_as_uint(x);
  return (u + 0x7fffu + ((u >> 16) & 1u)) >> 16;
}

__device__ __forceinline__ void gload16(const void* g, void* l) {
  __builtin_amdgcn_global_load_lds(
      (const __attribute__((address_space(1))) void*)g,
      (__attribute__((address_space(3))) void*)l, 16, 0, 0);
}

// ---------------- kernel 0: W_e transpose + f32->bf16 ----------------
__global__ __launch_bounds__(256) void we_transpose(
    const float* __restrict__ We, ushort_t* __restrict__ Wbt) {
  const int e  = blockIdx.z;
  const int d0 = blockIdx.y * 64;
  const int o0 = blockIdx.x * 64;
  __shared__ float t[64][65];
  const int tx = threadIdx.x & 15, ty = threadIdx.x >> 4;

  const float* src = We + ((size_t)e * D_ + d0) * O_ + o0;
#pragma unroll
  for (int p = 0; p < 4; ++p) {
    int dl = ty + p * 16;
    float4 v = *(const float4*)(src + (size_t)dl * O_ + tx * 4);
    t[dl][tx * 4 + 0] = v.x; t[dl][tx * 4 + 1] = v.y;
    t[dl][tx * 4 + 2] = v.z; t[dl][tx * 4 + 3] = v.w;
  }
  __syncthreads();
  ushort_t* dst = Wbt + ((size_t)e * O_ + o0) * D_ + d0;
#pragma unroll
  for (int p = 0; p < 4; ++p) {
    int ol = ty + p * 16;
    uint2 pk;
    pk.x = bf16_rne(t[tx * 4 + 0][ol]) | (bf16_rne(t[tx * 4 + 1][ol]) << 16);
    pk.y = bf16_rne(t[tx * 4 + 2][ol]) | (bf16_rne(t[tx * 4 + 3][ol]) << 16);
    *(uint2*)(dst + (size_t)ol * D_ + tx * 4) = pk;
  }
}

// ---------------- kernel 1: router (fp32) + feat cvt ----------------
// 1024 blocks x 256 thr (4 waves); wave owns 2 tokens; block = 8 tokens.
// Lane owns contiguous float4 d-slice per iter: 18 independent 16B loads
// in flight (deep MLP). W_r (256 KB) served from L1/L2, coalesced 64B/row.
__global__ __launch_bounds__(256) void router(
    const float* __restrict__ feat, const float* __restrict__ Wr,
    const float* __restrict__ br, ushort_t* __restrict__ featbf,
    int* __restrict__ tokL, float* __restrict__ wgtL, int* __restrict__ cntA,
    float* __restrict__ pisum) {
  __shared__ float pacc[16];
  const int tid = threadIdx.x;
  const int lane = tid & 63, w = tid >> 6;
  if (tid < 16) pacc[tid] = 0.f;
  __syncthreads();

  const int tbase = blockIdx.x * 8 + w * 2;
  f32x4 acc[2][4] = {};  // acc[i][q][c] = token i, expert q*4+c

  for (int si = 0; si < 16; ++si) {
    const int d4 = si * 256 + lane * 4;
    f32x4 f[2];
#pragma unroll
    for (int i = 0; i < 2; ++i)
      f[i] = *(const f32x4*)&feat[(size_t)(tbase + i) * D_ + d4];
    f32x4 wr[16];  // wr[j*4+q] = W_r[d4+j][q*4 .. q*4+3]
#pragma unroll
    for (int j = 0; j < 4; ++j) {
      const f32x4* wp = (const f32x4*)&Wr[(size_t)(d4 + j) * 16];
#pragma unroll
      for (int q = 0; q < 4; ++q) wr[j * 4 + q] = wp[q];
    }
#pragma unroll
    for (int i = 0; i < 2; ++i) {
      uint2 pk;
      pk.x = bf16_rne(f[i][0]) | (bf16_rne(f[i][1]) << 16);
      pk.y = bf16_rne(f[i][2]) | (bf16_rne(f[i][3]) << 16);
      *(uint2*)&featbf[(size_t)(tbase + i) * D_ + d4] = pk;
    }
#pragma unroll
    for (int i = 0; i < 2; ++i)
#pragma unroll
      for (int j = 0; j < 4; ++j) {
        const float fv = f[i][j];
#pragma unroll
        for (int q = 0; q < 4; ++q)
#pragma unroll
          for (int c = 0; c < 4; ++c)
            acc[i][q][c] = fmaf(fv, wr[j * 4 + q][c], acc[i][q][c]);
      }
  }

#pragma unroll
  for (int i = 0; i < 2; ++i) {
    float l[16];
#pragma unroll
    for (int e = 0; e < 16; ++e) {
      float v = acc[i][e >> 2][e & 3];
#pragma unroll
      for (int m = 32; m >= 1; m >>= 1) v += __shfl_xor(v, m, 64);
      l[e] = v + br[e];
    }
    float mx = l[0];
#pragma unroll
    for (int e = 1; e < 16; ++e) mx = fmaxf(mx, l[e]);
    float p[16];
    float s = 0.f;
#pragma unroll
    for (int e = 0; e < 16; ++e) { p[e] = expf(l[e] - mx); s += p[e]; }
    float inv = 1.f / s;
#pragma unroll
    for (int e = 0; e < 16; ++e) p[e] *= inv;
    // top-2 on probs, first-occurrence tie rule (matches lax.top_k)
    int i0 = 0; float v0 = p[0];
#pragma unroll
    for (int e = 1; e < 16; ++e) if (p[e] > v0) { v0 = p[e]; i0 = e; }
    int i1 = (i0 == 0) ? 1 : 0; float v1 = p[i1];
#pragma unroll
    for (int e = 0; e < 16; ++e)
      if (e != i0 && p[e] > v1) { v1 = p[e]; i1 = e; }
    float denom = fmaxf(v0 + v1, 1e-9f);
    float w0_ = v0 / denom, w1_ = v1 / denom;
    if (lane == 0) {
      int t = tbase + i;
      int s0 = atomicAdd(&cntA[i0], 1);
      tokL[i0 * B_ + s0] = t; wgtL[i0 * B_ + s0] = w0_;
      int s1 = atomicAdd(&cntA[i1], 1);
      tokL[i1 * B_ + s1] = t; wgtL[i1 * B_ + s1] = w1_;
#pragma unroll
      for (int e = 0; e < 16; ++e) atomicAdd(&pacc[e], p[e]);
    }
  }
  __syncthreads();
  if (tid < 16) atomicAdd(&pisum[tid], pacc[tid]);
}

// ---------------- kernel 2: grouped expert GEMM ----------------
// 128x128 tile, BK=64, 4 waves (2x2), dbuf LDS 64 KiB, gload_lds staging.
// LDS row = 64 bf16 = 128 B = 8 slots of 16 B; slot s holds k-group
// kg = s ^ (row&7)  (both-sides swizzle: source pre-swizzled, read swizzled).
__global__ __launch_bounds__(256, 2) void moe_gemm(
    const ushort_t* __restrict__ featbf, const ushort_t* __restrict__ Wbt,
    const float* __restrict__ be, const int* __restrict__ tokL,
    const float* __restrict__ wgtL, const int* __restrict__ cntA,
    float* __restrict__ out) {
  const int e = blockIdx.z;
  const int cnt = cntA[e];
  const int row0 = blockIdx.y * 128;
  if (row0 >= cnt) return;
  const int o0 = blockIdx.x * 128;
  const int tid = threadIdx.x;
  const int lane = tid & 63, w = tid >> 6;
  const int wm = w >> 1, wn = w & 1;

  __shared__ __align__(16) ushort_t As[2][128 * BK];
  __shared__ __align__(16) ushort_t Bs[2][128 * BK];

  const int rbase = w * 8 + (lane >> 3);
  const int kgc = (lane & 7) ^ (rbase & 7);
  const ushort_t* asrc[4];
  const ushort_t* bsrc[4];
#pragma unroll
  for (int j = 0; j < 4; ++j) {
    int r = j * 32 + rbase;
    int tr = row0 + r;
    int tok = (tr < cnt) ? tokL[e * B_ + tr] : 0;
    asrc[j] = featbf + (size_t)tok * D_ + kgc * 8;
    bsrc[j] = Wbt + ((size_t)e * O_ + o0 + r) * D_ + kgc * 8;
  }

  f32x4 acc[4][4] = {};
  const int lr = lane & 15;
  const int lg = lane >> 4;
  const int s0 = ((lg) ^ (lane & 7)) * 8;
  const int s1 = ((4 + lg) ^ (lane & 7)) * 8;

#define STAGE_ALL(buf, t)                                            \
  {                                                                  \
    ushort_t* ab = &As[buf][(w * 8) * BK];                           \
    ushort_t* bb = &Bs[buf][(w * 8) * BK];                           \
    _Pragma("unroll") for (int j = 0; j < 4; ++j) {                  \
      gload16(asrc[j] + (size_t)(t) * BK, ab + j * 32 * BK);         \
      gload16(bsrc[j] + (size_t)(t) * BK, bb + j * 32 * BK);         \
    }                                                                \
  }

#define COMPUTE(buf)                                                 \
  {                                                                  \
    _Pragma("unroll") for (int kk = 0; kk < 2; ++kk) {               \
      const int so = kk ? s1 : s0;                                   \
      bf16x8 af[4], bf[4];                                           \
      _Pragma("unroll") for (int m = 0; m < 4; ++m)                  \
          af[m] = *(const bf16x8*)&As[buf][(wm * 64 + m * 16 + lr) * BK + so]; \
      _Pragma("unroll") for (int n = 0; n < 4; ++n)                  \
          bf[n] = *(const bf16x8*)&Bs[buf][(wn * 64 + n * 16 + lr) * BK + so]; \
      _Pragma("unroll") for (int m = 0; m < 4; ++m)                  \
          _Pragma("unroll") for (int n = 0; n < 4; ++n)              \
              acc[m][n] = __builtin_amdgcn_mfma_f32_16x16x32_bf16(   \
                  af[m], bf[n], acc[m][n], 0, 0, 0);                 \
    }                                                                \
  }

  const int NT = D_ / BK;
  STAGE_ALL(0, 0);
  __syncthreads();
  for (int t = 0; t < NT - 1; ++t) {
    const int cur = t & 1;
    STAGE_ALL(cur ^ 1, t + 1);
    COMPUTE(cur);
    __syncthreads();
  }
  COMPUTE((NT - 1) & 1);

#pragma unroll
  for (int m = 0; m < 4; ++m) {
#pragma unroll
    for (int i = 0; i < 4; ++i) {
      int gr = row0 + wm * 64 + m * 16 + (lane >> 4) * 4 + i;
      if (gr < cnt) {
        int tk = tokL[e * B_ + gr];
        float wt = wgtL[e * B_ + gr];
#pragma unroll
        for (int n = 0; n < 4; ++n) {
          int o = o0 + wn * 64 + n * 16 + (lane & 15);
          float v = acc[m][n][i] + be[e * O_ + o];
          atomicAdd(&out[(size_t)tk * O_ + o], wt * v);
        }
      }
    }
  }
#undef STAGE_ALL
#undef COMPUTE
}

// ---------------- kernel 3: balance loss ----------------
__global__ void finalize(const float* __restrict__ pisum,
                         float* __restrict__ out) {
  if (threadIdx.x == 0) {
    float loss = 0.f;
#pragma unroll
    for (int e = 0; e < 16; ++e) {
      float pi = pisum[e] * (1.f / (float)B_);
      loss += pi * logf(fmaxf(pi, 1e-9f));
    }
    out[(size_t)B_ * O_] = 0.01f * (loss + logf(16.f));
  }
}

extern "C" void kernel_launch(void* const* d_in, const int* in_sizes, int n_in,
                              void* d_out, int out_size, void* d_ws,
                              size_t ws_size, hipStream_t stream) {
  const float* feat = (const float*)d_in[0];
  const float* Wr = (const float*)d_in[1];
  const float* br = (const float*)d_in[2];
  const float* We = (const float*)d_in[3];
  const float* be = (const float*)d_in[4];
  float* out = (float*)d_out;

  char* ws = (char*)d_ws;
  const size_t OFF_FEAT = 67108864;
  const size_t OFF_TOK  = OFF_FEAT + 67108864;
  const size_t OFF_WGT  = OFF_TOK + 524288;
  const size_t OFF_CNT  = OFF_WGT + 524288;
  const size_t OFF_PI   = OFF_CNT + 64;
  ushort_t* Wbt = (ushort_t*)ws;
  ushort_t* featbf = (ushort_t*)(ws + OFF_FEAT);
  int* tokL = (int*)(ws + OFF_TOK);
  float* wgtL = (float*)(ws + OFF_WGT);
  int* cntA = (int*)(ws + OFF_CNT);
  float* pisum = (float*)(ws + OFF_PI);

  hipMemsetAsync(out, 0, (size_t)(B_ * O_ + 1) * sizeof(float), stream);
  hipMemsetAsync(ws + OFF_CNT, 0, 128, stream);

  router<<<B_ / 8, 256, 0, stream>>>(feat, Wr, br, featbf, tokL, wgtL, cntA,
                                     pisum);
  we_transpose<<<dim3(O_ / 64, D_ / 64, E_), 256, 0, stream>>>(We, Wbt);
  moe_gemm<<<dim3(O_ / 128, B_ / 128, E_), 256, 0, stream>>>(
      featbf, Wbt, be, tokL, wgtL, cntA, out);
  finalize<<<1, 64, 0, stream>>>(pisum, out);
}

// Round 4
// 448.099 us; speedup vs baseline: 1.2818x; 1.2818x over previous
//
#include <hip/hip_runtime.h>

// TopK MoE classifier: B=8192, D=4096, E=16, O=512, top-2.
//  k1: router_mlp  fp32 logits/top-2 + fused feat f32->bf16; NO global
//      atomics: per-token records + per-block prob partials
//  k1b: bucket     16 blocks (1/expert), deterministic ballot compaction
//       of token records into per-expert lists; writes cntA
//  k0: we_transpose  W_e [E][D][O] f32 -> Wbt [E][O][D] bf16
//  k2: moe_gemm    grouped bf16 MFMA, 128x128 tile, BK=64, dbuf LDS,
//      global_load_lds staging w/ source-side XOR swizzle, 1 barrier/K-step
//  k3: finalize    balance loss from pblk partials (deterministic reduce)
// ws: [0,64Mi) Wbt | [64Mi,128Mi) featbf | tokL | wgtL | cntA | idxP | wP | pblk

#define B_ 8192
#define D_ 4096
#define E_ 16
#define O_ 512
#define BK 64

typedef unsigned int uint32;
typedef unsigned short ushort_t;
typedef __bf16 bf16_t;
typedef bf16_t bf16x8 __attribute__((ext_vector_type(8)));
typedef float f32x4 __attribute__((ext_vector_type(4)));

__device__ __forceinline__ uint32 bf16_rne(float x) {
  uint32 u = __float_as_uint(x);
  return (u + 0x7fffu + ((u >> 16) & 1u)) >> 16;
}

__device__ __forceinline__ void gload16(const void* g, void* l) {
  __builtin_amdgcn_global_load_lds(
      (const __attribute__((address_space(1))) void*)g,
      (__attribute__((address_space(3))) void*)l, 16, 0, 0);
}

// ---------------- kernel 0: W_e transpose + f32->bf16 ----------------
__global__ __launch_bounds__(256) void we_transpose(
    const float* __restrict__ We, ushort_t* __restrict__ Wbt) {
  const int e  = blockIdx.z;
  const int d0 = blockIdx.y * 64;
  const int o0 = blockIdx.x * 64;
  __shared__ float t[64][65];
  const int tx = threadIdx.x & 15, ty = threadIdx.x >> 4;

  const float* src = We + ((size_t)e * D_ + d0) * O_ + o0;
#pragma unroll
  for (int p = 0; p < 4; ++p) {
    int dl = ty + p * 16;
    float4 v = *(const float4*)(src + (size_t)dl * O_ + tx * 4);
    t[dl][tx * 4 + 0] = v.x; t[dl][tx * 4 + 1] = v.y;
    t[dl][tx * 4 + 2] = v.z; t[dl][tx * 4 + 3] = v.w;
  }
  __syncthreads();
  ushort_t* dst = Wbt + ((size_t)e * O_ + o0) * D_ + d0;
#pragma unroll
  for (int p = 0; p < 4; ++p) {
    int ol = ty + p * 16;
    uint2 pk;
    pk.x = bf16_rne(t[tx * 4 + 0][ol]) | (bf16_rne(t[tx * 4 + 1][ol]) << 16);
    pk.y = bf16_rne(t[tx * 4 + 2][ol]) | (bf16_rne(t[tx * 4 + 3][ol]) << 16);
    *(uint2*)(dst + (size_t)ol * D_ + tx * 4) = pk;
  }
}

// ---------------- kernel 1: router MLP (fp32) + feat cvt ----------------
// 512 blocks x 256 thr (4 waves); wave owns 4 tokens; NO global atomics.
__global__ __launch_bounds__(256) void router_mlp(
    const float* __restrict__ feat, const float* __restrict__ Wr,
    const float* __restrict__ br, ushort_t* __restrict__ featbf,
    int* __restrict__ idxP, float2* __restrict__ wP,
    float* __restrict__ pblk) {
  __shared__ float pw[4][16];
  const int tid = threadIdx.x;
  const int lane = tid & 63, w = tid >> 6;
  const int tbase = blockIdx.x * 16 + w * 4;

  f32x4 acc[4][4] = {};  // acc[token][q][c] = expert q*4+c

  for (int si = 0; si < 8; ++si) {
    const int d8 = si * 512 + lane * 8;
    f32x4 fa[4], fb[4];
#pragma unroll
    for (int i = 0; i < 4; ++i) {
      const float* fp = &feat[(size_t)(tbase + i) * D_ + d8];
      fa[i] = *(const f32x4*)fp;
      fb[i] = *(const f32x4*)(fp + 4);
    }
#pragma unroll
    for (int i = 0; i < 4; ++i) {
      uint4 pk;
      pk.x = bf16_rne(fa[i][0]) | (bf16_rne(fa[i][1]) << 16);
      pk.y = bf16_rne(fa[i][2]) | (bf16_rne(fa[i][3]) << 16);
      pk.z = bf16_rne(fb[i][0]) | (bf16_rne(fb[i][1]) << 16);
      pk.w = bf16_rne(fb[i][2]) | (bf16_rne(fb[i][3]) << 16);
      *(uint4*)&featbf[(size_t)(tbase + i) * D_ + d8] = pk;
    }
#pragma unroll
    for (int j = 0; j < 8; ++j) {
      const f32x4* wp = (const f32x4*)&Wr[(size_t)(d8 + j) * 16];
      f32x4 w0 = wp[0], w1 = wp[1], w2 = wp[2], w3 = wp[3];
#pragma unroll
      for (int i = 0; i < 4; ++i) {
        const float fv = (j < 4) ? fa[i][j] : fb[i][j - 4];
#pragma unroll
        for (int c = 0; c < 4; ++c) {
          acc[i][0][c] = fmaf(fv, w0[c], acc[i][0][c]);
          acc[i][1][c] = fmaf(fv, w1[c], acc[i][1][c]);
          acc[i][2][c] = fmaf(fv, w2[c], acc[i][2][c]);
          acc[i][3][c] = fmaf(fv, w3[c], acc[i][3][c]);
        }
      }
    }
  }

  float psum[16];
#pragma unroll
  for (int e = 0; e < 16; ++e) psum[e] = 0.f;

#pragma unroll
  for (int i = 0; i < 4; ++i) {
    float l[16];
#pragma unroll
    for (int e = 0; e < 16; ++e) {
      float v = acc[i][e >> 2][e & 3];
#pragma unroll
      for (int m = 32; m >= 1; m >>= 1) v += __shfl_xor(v, m, 64);
      l[e] = v + br[e];
    }
    float mx = l[0];
#pragma unroll
    for (int e = 1; e < 16; ++e) mx = fmaxf(mx, l[e]);
    float p[16];
    float s = 0.f;
#pragma unroll
    for (int e = 0; e < 16; ++e) { p[e] = expf(l[e] - mx); s += p[e]; }
    float inv = 1.f / s;
#pragma unroll
    for (int e = 0; e < 16; ++e) { p[e] *= inv; psum[e] += p[e]; }
    // top-2 on probs, first-occurrence tie rule (matches lax.top_k)
    int i0 = 0; float v0 = p[0];
#pragma unroll
    for (int e = 1; e < 16; ++e) if (p[e] > v0) { v0 = p[e]; i0 = e; }
    int i1 = (i0 == 0) ? 1 : 0; float v1 = p[i1];
#pragma unroll
    for (int e = 0; e < 16; ++e)
      if (e != i0 && p[e] > v1) { v1 = p[e]; i1 = e; }
    float denom = fmaxf(v0 + v1, 1e-9f);
    if (lane == 0) {
      int t = tbase + i;
      idxP[t] = i0 | (i1 << 8);
      wP[t] = make_float2(v0 / denom, v1 / denom);
    }
  }
  if (lane == 0) {
#pragma unroll
    for (int e = 0; e < 16; ++e) pw[w][e] = psum[e];
  }
  __syncthreads();
  if (tid < 16)
    pblk[blockIdx.x * 16 + tid] =
        (pw[0][tid] + pw[1][tid]) + (pw[2][tid] + pw[3][tid]);
}

// ---------------- kernel 1b: deterministic expert bucketing ----------------
// 16 blocks (1/expert) x 256 thr. Ballot/popcount compaction, token order.
__global__ __launch_bounds__(256) void bucket(
    const int* __restrict__ idxP, const float2* __restrict__ wP,
    int* __restrict__ tokL, float* __restrict__ wgtL, int* __restrict__ cntA) {
  const int e = blockIdx.x;
  const int tid = threadIdx.x, lane = tid & 63, w = tid >> 6;
  __shared__ int wsum[4];
  __shared__ int basev;
  if (tid == 0) basev = 0;
  __syncthreads();

  for (int c = 0; c < B_; c += 256) {
    const int t = c + tid;
    const int pk = idxP[t];
    const float2 wv = wP[t];
    const bool m0 = (pk & 255) == e;
    const bool m1 = (pk >> 8) == e;
    const bool m = m0 || m1;  // i0 != i1 -> at most one matches
    const float wt = m0 ? wv.x : wv.y;
    unsigned long long bal = __ballot(m);
    int rank = __popcll(bal & ((1ull << lane) - 1ull));
    if (lane == 0) wsum[w] = __popcll(bal);
    __syncthreads();
    int wbase = basev;
    for (int q = 0; q < w; ++q) wbase += wsum[q];
    if (m) {
      int pos = wbase + rank;
      tokL[e * B_ + pos] = t;
      wgtL[e * B_ + pos] = wt;
    }
    __syncthreads();
    if (tid == 0) basev += (wsum[0] + wsum[1]) + (wsum[2] + wsum[3]);
  }
  __syncthreads();
  if (tid == 0) cntA[e] = basev;
}

// ---------------- kernel 2: grouped expert GEMM ----------------
// 128x128 tile, BK=64, 4 waves (2x2), dbuf LDS 64 KiB, gload_lds staging.
// LDS row = 64 bf16 = 128 B = 8 slots of 16 B; slot s holds k-group
// kg = s ^ (row&7)  (both-sides swizzle: source pre-swizzled, read swizzled).
__global__ __launch_bounds__(256, 2) void moe_gemm(
    const ushort_t* __restrict__ featbf, const ushort_t* __restrict__ Wbt,
    const float* __restrict__ be, const int* __restrict__ tokL,
    const float* __restrict__ wgtL, const int* __restrict__ cntA,
    float* __restrict__ out) {
  const int e = blockIdx.z;
  const int cnt = cntA[e];
  const int row0 = blockIdx.y * 128;
  if (row0 >= cnt) return;
  const int o0 = blockIdx.x * 128;
  const int tid = threadIdx.x;
  const int lane = tid & 63, w = tid >> 6;
  const int wm = w >> 1, wn = w & 1;

  __shared__ __align__(16) ushort_t As[2][128 * BK];
  __shared__ __align__(16) ushort_t Bs[2][128 * BK];

  const int rbase = w * 8 + (lane >> 3);
  const int kgc = (lane & 7) ^ (rbase & 7);
  const ushort_t* asrc[4];
  const ushort_t* bsrc[4];
#pragma unroll
  for (int j = 0; j < 4; ++j) {
    int r = j * 32 + rbase;
    int tr = row0 + r;
    int tok = (tr < cnt) ? tokL[e * B_ + tr] : 0;
    asrc[j] = featbf + (size_t)tok * D_ + kgc * 8;
    bsrc[j] = Wbt + ((size_t)e * O_ + o0 + r) * D_ + kgc * 8;
  }

  f32x4 acc[4][4] = {};
  const int lr = lane & 15;
  const int lg = lane >> 4;
  const int s0 = ((lg) ^ (lane & 7)) * 8;
  const int s1 = ((4 + lg) ^ (lane & 7)) * 8;

#define STAGE_ALL(buf, t)                                            \
  {                                                                  \
    ushort_t* ab = &As[buf][(w * 8) * BK];                           \
    ushort_t* bb = &Bs[buf][(w * 8) * BK];                           \
    _Pragma("unroll") for (int j = 0; j < 4; ++j) {                  \
      gload16(asrc[j] + (size_t)(t) * BK, ab + j * 32 * BK);         \
      gload16(bsrc[j] + (size_t)(t) * BK, bb + j * 32 * BK);         \
    }                                                                \
  }

#define COMPUTE(buf)                                                 \
  {                                                                  \
    _Pragma("unroll") for (int kk = 0; kk < 2; ++kk) {               \
      const int so = kk ? s1 : s0;                                   \
      bf16x8 af[4], bf[4];                                           \
      _Pragma("unroll") for (int m = 0; m < 4; ++m)                  \
          af[m] = *(const bf16x8*)&As[buf][(wm * 64 + m * 16 + lr) * BK + so]; \
      _Pragma("unroll") for (int n = 0; n < 4; ++n)                  \
          bf[n] = *(const bf16x8*)&Bs[buf][(wn * 64 + n * 16 + lr) * BK + so]; \
      _Pragma("unroll") for (int m = 0; m < 4; ++m)                  \
          _Pragma("unroll") for (int n = 0; n < 4; ++n)              \
              acc[m][n] = __builtin_amdgcn_mfma_f32_16x16x32_bf16(   \
                  af[m], bf[n], acc[m][n], 0, 0, 0);                 \
    }                                                                \
  }

  const int NT = D_ / BK;
  STAGE_ALL(0, 0);
  __syncthreads();
  for (int t = 0; t < NT - 1; ++t) {
    const int cur = t & 1;
    STAGE_ALL(cur ^ 1, t + 1);
    COMPUTE(cur);
    __syncthreads();
  }
  COMPUTE((NT - 1) & 1);

#pragma unroll
  for (int m = 0; m < 4; ++m) {
#pragma unroll
    for (int i = 0; i < 4; ++i) {
      int gr = row0 + wm * 64 + m * 16 + (lane >> 4) * 4 + i;
      if (gr < cnt) {
        int tk = tokL[e * B_ + gr];
        float wt = wgtL[e * B_ + gr];
#pragma unroll
        for (int n = 0; n < 4; ++n) {
          int o = o0 + wn * 64 + n * 16 + (lane & 15);
          float v = acc[m][n][i] + be[e * O_ + o];
          atomicAdd(&out[(size_t)tk * O_ + o], wt * v);
        }
      }
    }
  }
#undef STAGE_ALL
#undef COMPUTE
}

// ---------------- kernel 3: balance loss ----------------
__global__ __launch_bounds__(64) void finalize(const float* __restrict__ pblk,
                                               float* __restrict__ out) {
  __shared__ float red[64];
  const int tid = threadIdx.x;
  const int e = tid & 15, g = tid >> 4;
  float s = 0.f;
  for (int b = g; b < 512; b += 4) s += pblk[b * 16 + e];
  red[tid] = s;
  __syncthreads();
  if (tid < 16) {
    float tot = (red[tid] + red[16 + tid]) + (red[32 + tid] + red[48 + tid]);
    float pi = tot * (1.f / (float)B_);
    red[tid] = pi * logf(fmaxf(pi, 1e-9f));
  }
  __syncthreads();
  if (tid == 0) {
    float loss = 0.f;
#pragma unroll
    for (int e2 = 0; e2 < 16; ++e2) loss += red[e2];
    out[(size_t)B_ * O_] = 0.01f * (loss + logf(16.f));
  }
}

extern "C" void kernel_launch(void* const* d_in, const int* in_sizes, int n_in,
                              void* d_out, int out_size, void* d_ws,
                              size_t ws_size, hipStream_t stream) {
  const float* feat = (const float*)d_in[0];
  const float* Wr = (const float*)d_in[1];
  const float* br = (const float*)d_in[2];
  const float* We = (const float*)d_in[3];
  const float* be = (const float*)d_in[4];
  float* out = (float*)d_out;

  char* ws = (char*)d_ws;
  const size_t OFF_FEAT = 67108864;             // 64 MiB Wbt
  const size_t OFF_TOK  = OFF_FEAT + 67108864;  // 64 MiB featbf
  const size_t OFF_WGT  = OFF_TOK + 524288;
  const size_t OFF_CNT  = OFF_WGT + 524288;
  const size_t OFF_IDX  = OFF_CNT + 256;
  const size_t OFF_WP   = OFF_IDX + 32768;      // idxP: 8192 int
  const size_t OFF_PB   = OFF_WP + 65536;       // wP: 8192 float2
  ushort_t* Wbt = (ushort_t*)ws;
  ushort_t* featbf = (ushort_t*)(ws + OFF_FEAT);
  int* tokL = (int*)(ws + OFF_TOK);
  float* wgtL = (float*)(ws + OFF_WGT);
  int* cntA = (int*)(ws + OFF_CNT);
  int* idxP = (int*)(ws + OFF_IDX);
  float2* wP = (float2*)(ws + OFF_WP);
  float* pblk = (float*)(ws + OFF_PB);          // 512*16 floats

  hipMemsetAsync(out, 0, (size_t)(B_ * O_ + 1) * sizeof(float), stream);

  router_mlp<<<B_ / 16, 256, 0, stream>>>(feat, Wr, br, featbf, idxP, wP, pblk);
  bucket<<<E_, 256, 0, stream>>>(idxP, wP, tokL, wgtL, cntA);
  we_transpose<<<dim3(O_ / 64, D_ / 64, E_), 256, 0, stream>>>(We, Wbt);
  moe_gemm<<<dim3(O_ / 128, B_ / 128, E_), 256, 0, stream>>>(
      featbf, Wbt, be, tokL, wgtL, cntA, out);
  finalize<<<1, 64, 0, stream>>>(pblk, out);
}